// Round 11
// baseline (165.090 us; speedup 1.0000x reference)
//
#include <hip/hip_runtime.h>
#include <hip/hip_bf16.h>
#include <stdint.h>

// Problem constants (fixed by setup_inputs)
#define T_SEQ  2048
#define DMODEL 1024
#define NBATCH 2
#define NHEAD  16
#define DHEAD  64
#define MTOT   (NBATCH * T_SEQ)   // 4096 rows for all projection GEMMs

typedef __attribute__((ext_vector_type(8))) short short8_t;   // 8 bf16 (4 VGPRs) MFMA A/B frag
typedef __attribute__((ext_vector_type(4))) float f32x4;      // 16x16 MFMA C/D frag
typedef __attribute__((ext_vector_type(16))) float f32x16;    // 32x32 MFMA C/D frag
typedef __attribute__((ext_vector_type(2))) __bf16 bhalf2_t;
typedef __attribute__((ext_vector_type(4))) uint32_t uint4_t;

typedef const __attribute__((address_space(1))) void* gas_t;
typedef __attribute__((address_space(3))) void* las_t;

// Native f32->bf16 (gfx950 v_cvt_pk_bf16_f32, RNE).
__device__ __forceinline__ ushort f2bf(float f) {
    return __builtin_bit_cast(unsigned short, (__bf16)f);
}
__device__ __forceinline__ uint32_t pk_bf16(float a, float b) {  // one v_cvt_pk_bf16_f32
    bhalf2_t t; t[0] = (__bf16)a; t[1] = (__bf16)b;
    return __builtin_bit_cast(uint32_t, t);
}

// Zero-shuffle P->A-frag: pack 8 consecutive S registers as the frag. The induced
// k->kv permutation pi (swap quads 1<->2 within each 16) is absorbed into the V LDS
// column layout at write time, so no cross-lane exchange is needed at all.
template <int B>
__device__ __forceinline__ short8_t pack8(const f32x16 &s) {
    uint4_t u;
    u[0] = pk_bf16(s[B + 0], s[B + 1]);
    u[1] = pk_bf16(s[B + 2], s[B + 3]);
    u[2] = pk_bf16(s[B + 4], s[B + 5]);
    u[3] = pk_bf16(s[B + 6], s[B + 7]);
    return __builtin_bit_cast(short8_t, u);
}

// ---------------- fp32 -> bf16 convert of q,k,v into one contiguous [3][4096][1024] ----------------
__global__ __launch_bounds__(256) void convert_qkv_kernel(
        const float* __restrict__ q, const float* __restrict__ k,
        const float* __restrict__ v, ushort* __restrict__ outb) {
    const size_t per = (size_t)MTOT * DMODEL / 4;           // float4s per tensor = 1048576
    size_t idx = (size_t)blockIdx.x * 256 + threadIdx.x;
    int t = (int)(idx / per);
    size_t i = idx - (size_t)t * per;
    const float4* src = (const float4*)(t == 0 ? q : (t == 1 ? k : v));
    float4 val = src[i];
    uint2 o;
    o.x = pk_bf16(val.x, val.y);
    o.y = pk_bf16(val.z, val.w);
    ((uint2*)outb)[(size_t)t * per + i] = o;
}

// ---- W fp32 [K][N] -> bf16 transposed [N][K]; Wq gets 1/sqrt(dk)*log2(e) folded in (exp2 domain) --
__global__ __launch_bounds__(256) void convw_kernel(
        const float* __restrict__ Wq, const float* __restrict__ Wk,
        const float* __restrict__ Wv, const float* __restrict__ Wo,
        ushort* __restrict__ wt) {
    __shared__ float tile[32][33];                          // +1 pad: conflict-free transpose
    int z = blockIdx.z;
    const float* W = z == 0 ? Wq : z == 1 ? Wk : z == 2 ? Wv : Wo;
    const float sc = (z == 0) ? 0.18033688011f : 1.0f;      // 0.125 * log2(e)
    ushort* out = wt + (size_t)z * DMODEL * DMODEL;
    int tx = threadIdx.x, ty = threadIdx.y;                 // 32 x 8
    int k0 = blockIdx.x * 32, n0 = blockIdx.y * 32;
    #pragma unroll
    for (int i = 0; i < 4; i++)
        tile[ty + i * 8][tx] = W[(size_t)(k0 + ty + i * 8) * DMODEL + n0 + tx];
    __syncthreads();
    #pragma unroll
    for (int i = 0; i < 4; i++)
        out[(size_t)(n0 + ty + i * 8) * DMODEL + k0 + tx] = f2bf(tile[tx][ty + i * 8] * sc);
}

// ---------------- bf16 GEMM, m97 structure: C[M][N] = A[M][K] * Bt[N][K]^T ----------------
template <bool OUT_F32>
__global__ __launch_bounds__(256, 2) void gemm_bt_kernel(
        const ushort* __restrict__ Aall, const ushort* __restrict__ Btall,
        void* __restrict__ Call, int M, int N, int K) {
    const ushort* A  = Aall  + (size_t)blockIdx.z * M * K;
    const ushort* Bt = Btall + (size_t)blockIdx.z * N * K;

    __shared__ ushort As[128 * 32];   // [128 rows][32 k] row-major, 8 KB
    __shared__ ushort Bs[128 * 32];

    const int tid  = threadIdx.x;
    const int lane = tid & 63;
    const int wid  = tid >> 6;
    const int wr = wid >> 1, wc = wid & 1;          // 2x2 wave grid, 64x64 out each
    const int m_base = blockIdx.x * 128;
    const int n_base = blockIdx.y * 128;

    f32x4 acc[4][4] = {};

    const int srow = lane >> 2;                     // staging: 16 rows / chunk
    const int scol = (lane & 3) * 8;                // 4 x 16B per row

    for (int kk = 0; kk < K; kk += 32) {
        __syncthreads();
        #pragma unroll
        for (int i = 0; i < 2; i++) {
            int c = wid * 2 + i;
            const ushort* ga = A  + (size_t)(m_base + c * 16 + srow) * K + kk + scol;
            const ushort* gb = Bt + (size_t)(n_base + c * 16 + srow) * K + kk + scol;
            __builtin_amdgcn_global_load_lds((gas_t)ga, (las_t)(As + c * 512), 16, 0, 0);
            __builtin_amdgcn_global_load_lds((gas_t)gb, (las_t)(Bs + c * 512), 16, 0, 0);
        }
        __syncthreads();
        short8_t a[4], b[4];
        #pragma unroll
        for (int mt = 0; mt < 4; mt++)
            a[mt] = *(const short8_t*)(As + (wr * 64 + mt * 16 + (lane & 15)) * 32 + (lane >> 4) * 8);
        #pragma unroll
        for (int nt = 0; nt < 4; nt++)
            b[nt] = *(const short8_t*)(Bs + (wc * 64 + nt * 16 + (lane & 15)) * 32 + (lane >> 4) * 8);
        #pragma unroll
        for (int mt = 0; mt < 4; mt++)
            #pragma unroll
            for (int nt = 0; nt < 4; nt++)
                acc[mt][nt] = __builtin_amdgcn_mfma_f32_16x16x32_bf16(a[mt], b[nt], acc[mt][nt], 0, 0, 0);
    }

    const int row0 = m_base + wr * 64 + (lane >> 4) * 4;
    const int col0 = n_base + wc * 64 + (lane & 15);
    if constexpr (OUT_F32) {
        float* C = (float*)Call + (size_t)blockIdx.z * M * N;
        #pragma unroll
        for (int mt = 0; mt < 4; mt++)
            #pragma unroll
            for (int nt = 0; nt < 4; nt++)
                #pragma unroll
                for (int r = 0; r < 4; r++)
                    C[(size_t)(row0 + mt * 16 + r) * N + col0 + nt * 16] = acc[mt][nt][r];
    } else {
        ushort* C = (ushort*)Call + (size_t)blockIdx.z * M * N;
        #pragma unroll
        for (int mt = 0; mt < 4; mt++)
            #pragma unroll
            for (int nt = 0; nt < 4; nt++)
                #pragma unroll
                for (int r = 0; r < 4; r++)
                    C[(size_t)(row0 + mt * 16 + r) * N + col0 + nt * 16] = f2bf(acc[mt][nt][r]);
    }
}

// ---------------- causal flash attention: 1-wave pair blocks, counted-vmcnt pipeline ----------------
// grid = 1024 one-wave blocks (64 thr): block = pair (qb=u, 63-u) of one (b,h), processed
// sequentially -> exactly 33 KV-tiles per block under ANY dispatch order (no scheduler
// assumptions). No barriers (single wave). K staged via global_load_lds DIRECT into an
// unpadded [64][64] LDS buffer with pre-swizzled per-lane global source (chunk ^= row&7) ->
// conflict-free reads, zero staging VALU/VGPR for K. V reg-staged with v_perm transpose into
// pad-72 LDS (measured conflict-free). Single-wave software pipeline with counted vmcnt:
//   {vmcnt(8): K(t) ready; QK; issue K(t+1); softmax; vmcnt(8): V(t) ready; WRITEV;
//    issue V(t+1) loads; PV} -- loads stay in flight across the whole tile body.
// Swapped QK^T (mfma_32x32x16), in-register softmax, zero-shuffle PV (pi in V layout),
// exp2 domain, defer-max, setprio.
__global__ __launch_bounds__(64, 1) void attn_kernel(
        const ushort* __restrict__ Qp, const ushort* __restrict__ Kp,
        const ushort* __restrict__ Vp, ushort* __restrict__ Op) {
    __shared__ __attribute__((aligned(16))) ushort Ksh[64 * 64];  // unpadded (gload_lds dest)
    __shared__ __attribute__((aligned(16))) ushort Vts[64 * 72];  // [dv][kv-permuted], padded

    const int lane = threadIdx.x;          // one wave
    const int m31 = lane & 31, hi = lane >> 5;
    const int bx = (int)blockIdx.x;
    const int u = bx & 31, bh = bx >> 5;   // pair index, head index
    const int b = bh >> 4, h = bh & 15;

    const ushort* Qb = Qp + (size_t)(b * T_SEQ) * DMODEL + h * DHEAD;
    const ushort* Kb = Kp + (size_t)(b * T_SEQ) * DMODEL + h * DHEAD;
    const ushort* Vb = Vp + (size_t)(b * T_SEQ) * DMODEL + h * DHEAD;
    ushort* Ob = Op + (size_t)(b * T_SEQ) * DMODEL + h * DHEAD;

    const int na = (u >> 1) + 1;           // tiles in half A (qb=u); half B (qb=63-u): 32-(u>>1)

    // ---- K staging: gload_lds with source chunk swizzle (LDS[r][s] = G[r][s ^ (r&7)]) ----
    const int krow = lane >> 3;                       // row within 8-row group (== r&7)
    const int kchunk = (lane & 7) ^ krow;             // swizzled source 16B chunk
    auto ISSUE_K = [&](int kv0) {
        #pragma unroll
        for (int i = 0; i < 8; i++)
            __builtin_amdgcn_global_load_lds(
                (gas_t)(Kb + (size_t)(kv0 + 8 * i + krow) * DMODEL + kchunk * 8),
                (las_t)(Ksh + i * 512), 16, 0, 0);
    };
    const int kx = m31 & 7;                           // read-side XOR (chunk slot)

    // ---- V staging: reg loads + v_perm transpose into pad-72 (pi column permutation) ----
    const int kvp = lane & 31, dvh = lane >> 5;       // kv pair, dv half (32 cols)
    const int lp = kvp & 7, q2 = lp >> 1;
    const int q2p = ((q2 & 1) << 1) | (q2 >> 1);      // 0,1,2,3 -> 0,2,1,3
    const int kvc = (kvp & ~7) | (q2p << 1) | (lp & 1);

    short8_t vreg[8];
    auto LOADV = [&](int kv0) {
        const ushort* vsrc = Vb + (size_t)(kv0 + 2 * kvp) * DMODEL + dvh * 32;
        #pragma unroll
        for (int j = 0; j < 4; j++) {
            vreg[j]     = *(const short8_t*)(vsrc + j * 8);
            vreg[4 + j] = *(const short8_t*)(vsrc + DMODEL + j * 8);
        }
    };
    auto WRITEV = [&]() {
        #pragma unroll
        for (int j = 0; j < 4; j++) {
            uint4_t a = __builtin_bit_cast(uint4_t, vreg[j]);      // kv even row
            uint4_t o = __builtin_bit_cast(uint4_t, vreg[4 + j]);  // kv odd row
            #pragma unroll
            for (int jj = 0; jj < 4; jj++) {
                int d0 = dvh * 32 + j * 8 + 2 * jj;
                *(uint32_t*)(&Vts[(d0 + 0) * 72 + kvc * 2]) =
                    __builtin_amdgcn_perm(o[jj], a[jj], 0x05040100u);
                *(uint32_t*)(&Vts[(d0 + 1) * 72 + kvc * 2]) =
                    __builtin_amdgcn_perm(o[jj], a[jj], 0x07060302u);
            }
        }
    };

    // ---- per-half state ----
    int qb = u;
    int q0w = qb * 32, qg = q0w + m31;
    short8_t qf[4];
    #pragma unroll
    for (int dkc = 0; dkc < 4; dkc++)
        qf[dkc] = *(const short8_t*)(Qb + (size_t)(q0w + m31) * DMODEL + dkc * 16 + hi * 8);

    f32x16 acc0 = {}, acc1 = {};           // O[32q][64dv]: acc0 cols 0-31, acc1 cols 32-63
    float mrun = -1e30f, lrun = 0.f;

    auto WRITE_O = [&]() {
        float linv = __builtin_amdgcn_rcpf(lrun);
        #pragma unroll
        for (int r = 0; r < 16; r++) {
            int ql = (r & 3) + 8 * (r >> 2) + 4 * hi;
            float li = __shfl(linv, ql);
            ushort* orow = Ob + (size_t)(q0w + ql) * DMODEL + m31;
            orow[0]  = f2bf(acc0[r] * li);
            orow[32] = f2bf(acc1[r] * li);
        }
    };
    auto TILE = [&](int t) { return (t < na) ? t : t - na; };

    // ---- prologue: K(0) first (oldest), then V(0) ----
    ISSUE_K(TILE(0) * 64);
    LOADV(TILE(0) * 64);

    for (int tt = 0; tt < 33; ++tt) {
        if (tt == na) {                    // half boundary: finish A, start B, drain counters
            WRITE_O();
            acc0 = f32x16{}; acc1 = f32x16{};
            mrun = -1e30f; lrun = 0.f;
            qb = 63 - u; q0w = qb * 32; qg = q0w + m31;
            #pragma unroll
            for (int dkc = 0; dkc < 4; dkc++)
                qf[dkc] = *(const short8_t*)(Qb + (size_t)(q0w + m31) * DMODEL + dkc * 16 + hi * 8);
            asm volatile("s_waitcnt vmcnt(0)" ::: "memory");
            __builtin_amdgcn_sched_barrier(0);
        }
        const int t = TILE(tt);
        const int kv0 = t * 64;
        const bool need_mask = (t == (qb >> 1));

        // step 1: K(tt) staged (8 oldest loads complete; V(tt) regs may still be in flight)
        asm volatile("s_waitcnt vmcnt(8)" ::: "memory");
        __builtin_amdgcn_sched_barrier(0);

        // step 2: S^T = K * Q^T (exp2-domain scores)
        // lane holds S^T[kv][q=m31]: s0 = kv 0..31, s1 = kv 32..63;
        // reg r -> kv_local = (r&3) + 8*(r>>2) + 4*hi  [C/D layout, m74/m101]
        f32x16 s0 = {}, s1 = {};
        __builtin_amdgcn_s_setprio(1);
        #pragma unroll
        for (int dkc = 0; dkc < 4; dkc++) {
            short8_t kf0 = *(const short8_t*)(&Ksh[(m31) * 64 + (((dkc << 1) | hi) ^ kx) * 8]);
            short8_t kf1 = *(const short8_t*)(&Ksh[(32 + m31) * 64 + (((dkc << 1) | hi) ^ kx) * 8]);
            s0 = __builtin_amdgcn_mfma_f32_32x32x16_bf16(kf0, qf[dkc], s0, 0, 0, 0);
            s1 = __builtin_amdgcn_mfma_f32_32x32x16_bf16(kf1, qf[dkc], s1, 0, 0, 0);
        }
        __builtin_amdgcn_s_setprio(0);

        // step 3: issue next K tile (overwrites Ksh only after the reads above, same wave)
        if (tt + 1 < 33) ISSUE_K(TILE(tt + 1) * 64);

        // step 4: causal mask (diagonal tile only) + softmax
        if (need_mask) {
            const int kvb = kv0 + 4 * hi;
            #pragma unroll
            for (int r = 0; r < 16; r++) {
                int kvl = (r & 3) + 8 * (r >> 2);
                if (kvb + kvl      > qg) s0[r] = -1e30f;
                if (kvb + kvl + 32 > qg) s1[r] = -1e30f;
            }
        }
        float tm[16];
        #pragma unroll
        for (int r = 0; r < 16; r++) tm[r] = fmaxf(s0[r], s1[r]);
        #pragma unroll
        for (int st = 8; st >= 1; st >>= 1)
            #pragma unroll
            for (int i = 0; i < st; i++) tm[i] = fmaxf(tm[i], tm[i + st]);
        float pmax = fmaxf(tm[0], __shfl_xor(tm[0], 32));

        if (!__all(pmax <= mrun + 8.f)) {  // T13 defer-max
            float mnew = fmaxf(mrun, pmax);
            float fac = exp2f(mrun - mnew);
            mrun = mnew;
            lrun *= fac;
            #pragma unroll
            for (int r = 0; r < 16; r++) {
                float fr = __shfl(fac, (r & 3) + 8 * (r >> 2) + 4 * hi);
                acc0[r] *= fr; acc1[r] *= fr;
            }
        }
        float ps[16];
        #pragma unroll
        for (int r = 0; r < 16; r++) {
            s0[r] = exp2f(s0[r] - mrun);
            s1[r] = exp2f(s1[r] - mrun);
            ps[r] = s0[r] + s1[r];
        }
        #pragma unroll
        for (int st = 8; st >= 1; st >>= 1)
            #pragma unroll
            for (int i = 0; i < st; i++) ps[i] += ps[i + st];
        lrun += ps[0] + __shfl_xor(ps[0], 32);

        // step 5: V(tt) regs complete -> stage V into LDS
        if (tt == 32) { asm volatile("s_waitcnt vmcnt(0)" ::: "memory"); }
        else          { asm volatile("s_waitcnt vmcnt(8)" ::: "memory"); }
        __builtin_amdgcn_sched_barrier(0);
        WRITEV();

        // step 6: issue next V tile's global loads (latency hides under PV + next QK/softmax)
        if (tt + 1 < 33) LOADV(TILE(tt + 1) * 64);

        // step 7: P -> A-frags (zero-shuffle; V columns pre-permuted), O += P * V
        short8_t pa[4];
        pa[0] = pack8<0>(s0);              // kv block  0..15 (pi-ordered)
        pa[1] = pack8<8>(s0);              // kv block 16..31
        pa[2] = pack8<0>(s1);              // kv block 32..47
        pa[3] = pack8<8>(s1);              // kv block 48..63
        __builtin_amdgcn_s_setprio(1);
        #pragma unroll
        for (int ks = 0; ks < 4; ks++) {
            short8_t vf0 = *(const short8_t*)(&Vts[(m31) * 72 + ks * 16 + hi * 8]);
            short8_t vf1 = *(const short8_t*)(&Vts[(32 + m31) * 72 + ks * 16 + hi * 8]);
            acc0 = __builtin_amdgcn_mfma_f32_32x32x16_bf16(pa[ks], vf0, acc0, 0, 0, 0);
            acc1 = __builtin_amdgcn_mfma_f32_32x32x16_bf16(pa[ks], vf1, acc1, 0, 0, 0);
        }
        __builtin_amdgcn_s_setprio(0);
    }
    WRITE_O();
}

// ---------------- launch ----------------
extern "C" void kernel_launch(void* const* d_in, const int* in_sizes, int n_in,
                              void* d_out, int out_size, void* d_ws, size_t ws_size,
                              hipStream_t stream) {
    (void)in_sizes; (void)n_in; (void)out_size; (void)ws_size;
    const float* q  = (const float*)d_in[0];
    const float* k  = (const float*)d_in[1];
    const float* v  = (const float*)d_in[2];
    // d_in[3] = mask (causal tril) -- implemented analytically
    const float* Wq = (const float*)d_in[4];
    const float* Wk = (const float*)d_in[5];
    const float* Wv = (const float*)d_in[6];
    const float* Wo = (const float*)d_in[7];

    ushort* ws = (ushort*)d_ws;
    const size_t MK = (size_t)MTOT * DMODEL;    // 4194304 elems
    const size_t NK = (size_t)DMODEL * DMODEL;  // 1048576 elems
    ushort* qkvb = ws;                    // bf16 q,k,v        [3*MK]   (24 MB)
    ushort* wt   = ws + 3 * MK;           // bf16 W^T x4       [4*NK]   ( 8 MB)
    ushort* qkvp = ws + 3 * MK + 4 * NK;  // bf16 Q,K,V proj   [3*MK]   (24 MB)
    ushort* Op   = ws;                    // attn out reuses qkvb region ( 8 MB)

    convert_qkv_kernel<<<dim3(12288), dim3(256), 0, stream>>>(q, k, v, qkvb);
    convw_kernel<<<dim3(32, 32, 4), dim3(32, 8), 0, stream>>>(Wq, Wk, Wv, Wo, wt);
    gemm_bt_kernel<false><<<dim3(32, 8, 3), dim3(256), 0, stream>>>(qkvb, wt, (void*)qkvp,
                                                                    MTOT, DMODEL, DMODEL);
    attn_kernel<<<dim3(1024), dim3(64), 0, stream>>>(qkvp, qkvp + MK, qkvp + 2 * MK, Op);
    gemm_bt_kernel<true><<<dim3(32, 8, 1), dim3(256), 0, stream>>>(Op, wt + 3 * NK, d_out,
                                                                   MTOT, DMODEL, DMODEL);
}

// Round 12
// 145.123 us; speedup vs baseline: 1.1376x; 1.1376x over previous
//
#include <hip/hip_runtime.h>
#include <hip/hip_bf16.h>
#include <stdint.h>

// Problem constants (fixed by setup_inputs)
#define T_SEQ  2048
#define DMODEL 1024
#define NBATCH 2
#define NHEAD  16
#define DHEAD  64
#define MTOT   (NBATCH * T_SEQ)   // 4096 rows for all projection GEMMs

typedef __attribute__((ext_vector_type(8))) short short8_t;   // 8 bf16 (4 VGPRs) MFMA A/B frag
typedef __attribute__((ext_vector_type(4))) float f32x4;      // 16x16 MFMA C/D frag
typedef __attribute__((ext_vector_type(16))) float f32x16;    // 32x32 MFMA C/D frag
typedef __attribute__((ext_vector_type(2))) __bf16 bhalf2_t;
typedef __attribute__((ext_vector_type(4))) uint32_t uint4_t;

typedef const __attribute__((address_space(1))) void* gas_t;
typedef __attribute__((address_space(3))) void* las_t;

// Native f32->bf16 (gfx950 v_cvt_pk_bf16_f32, RNE).
__device__ __forceinline__ ushort f2bf(float f) {
    return __builtin_bit_cast(unsigned short, (__bf16)f);
}
__device__ __forceinline__ uint32_t pk_bf16(float a, float b) {  // one v_cvt_pk_bf16_f32
    bhalf2_t t; t[0] = (__bf16)a; t[1] = (__bf16)b;
    return __builtin_bit_cast(uint32_t, t);
}

// Zero-shuffle P->A-frag: pack 8 consecutive S registers as the frag. The induced
// k->kv permutation pi (swap quads 1<->2 within each 16) is absorbed into the V LDS
// column layout at write time, so no cross-lane exchange is needed at all.
template <int B>
__device__ __forceinline__ short8_t pack8(const f32x16 &s) {
    uint4_t u;
    u[0] = pk_bf16(s[B + 0], s[B + 1]);
    u[1] = pk_bf16(s[B + 2], s[B + 3]);
    u[2] = pk_bf16(s[B + 4], s[B + 5]);
    u[3] = pk_bf16(s[B + 6], s[B + 7]);
    return __builtin_bit_cast(short8_t, u);
}

// ---------------- fp32 -> bf16 convert of q,k,v into one contiguous [3][4096][1024] ----------------
__global__ __launch_bounds__(256) void convert_qkv_kernel(
        const float* __restrict__ q, const float* __restrict__ k,
        const float* __restrict__ v, ushort* __restrict__ outb) {
    const size_t per = (size_t)MTOT * DMODEL / 4;           // float4s per tensor = 1048576
    size_t idx = (size_t)blockIdx.x * 256 + threadIdx.x;
    int t = (int)(idx / per);
    size_t i = idx - (size_t)t * per;
    const float4* src = (const float4*)(t == 0 ? q : (t == 1 ? k : v));
    float4 val = src[i];
    uint2 o;
    o.x = pk_bf16(val.x, val.y);
    o.y = pk_bf16(val.z, val.w);
    ((uint2*)outb)[(size_t)t * per + i] = o;
}

// ---- W fp32 [K][N] -> bf16 transposed [N][K]; Wq gets 1/sqrt(dk)*log2(e) folded in (exp2 domain) --
__global__ __launch_bounds__(256) void convw_kernel(
        const float* __restrict__ Wq, const float* __restrict__ Wk,
        const float* __restrict__ Wv, const float* __restrict__ Wo,
        ushort* __restrict__ wt) {
    __shared__ float tile[32][33];                          // +1 pad: conflict-free transpose
    int z = blockIdx.z;
    const float* W = z == 0 ? Wq : z == 1 ? Wk : z == 2 ? Wv : Wo;
    const float sc = (z == 0) ? 0.18033688011f : 1.0f;      // 0.125 * log2(e)
    ushort* out = wt + (size_t)z * DMODEL * DMODEL;
    int tx = threadIdx.x, ty = threadIdx.y;                 // 32 x 8
    int k0 = blockIdx.x * 32, n0 = blockIdx.y * 32;
    #pragma unroll
    for (int i = 0; i < 4; i++)
        tile[ty + i * 8][tx] = W[(size_t)(k0 + ty + i * 8) * DMODEL + n0 + tx];
    __syncthreads();
    #pragma unroll
    for (int i = 0; i < 4; i++)
        out[(size_t)(n0 + ty + i * 8) * DMODEL + k0 + tx] = f2bf(tile[tx][ty + i * 8] * sc);
}

// ---------------- zero the work-queue counter (run before attn each launch) ----------------
__global__ void zero_ctr_kernel(uint32_t* ctr) {
    if (threadIdx.x == 0 && blockIdx.x == 0) *ctr = 0u;
}

// ---------------- bf16 GEMM, m97 structure: C[M][N] = A[M][K] * Bt[N][K]^T ----------------
template <bool OUT_F32>
__global__ __launch_bounds__(256, 2) void gemm_bt_kernel(
        const ushort* __restrict__ Aall, const ushort* __restrict__ Btall,
        void* __restrict__ Call, int M, int N, int K) {
    const ushort* A  = Aall  + (size_t)blockIdx.z * M * K;
    const ushort* Bt = Btall + (size_t)blockIdx.z * N * K;

    __shared__ ushort As[128 * 32];   // [128 rows][32 k] row-major, 8 KB
    __shared__ ushort Bs[128 * 32];

    const int tid  = threadIdx.x;
    const int lane = tid & 63;
    const int wid  = tid >> 6;
    const int wr = wid >> 1, wc = wid & 1;          // 2x2 wave grid, 64x64 out each
    const int m_base = blockIdx.x * 128;
    const int n_base = blockIdx.y * 128;

    f32x4 acc[4][4] = {};

    const int srow = lane >> 2;                     // staging: 16 rows / chunk
    const int scol = (lane & 3) * 8;                // 4 x 16B per row

    for (int kk = 0; kk < K; kk += 32) {
        __syncthreads();
        #pragma unroll
        for (int i = 0; i < 2; i++) {
            int c = wid * 2 + i;
            const ushort* ga = A  + (size_t)(m_base + c * 16 + srow) * K + kk + scol;
            const ushort* gb = Bt + (size_t)(n_base + c * 16 + srow) * K + kk + scol;
            __builtin_amdgcn_global_load_lds((gas_t)ga, (las_t)(As + c * 512), 16, 0, 0);
            __builtin_amdgcn_global_load_lds((gas_t)gb, (las_t)(Bs + c * 512), 16, 0, 0);
        }
        __syncthreads();
        short8_t a[4], b[4];
        #pragma unroll
        for (int mt = 0; mt < 4; mt++)
            a[mt] = *(const short8_t*)(As + (wr * 64 + mt * 16 + (lane & 15)) * 32 + (lane >> 4) * 8);
        #pragma unroll
        for (int nt = 0; nt < 4; nt++)
            b[nt] = *(const short8_t*)(Bs + (wc * 64 + nt * 16 + (lane & 15)) * 32 + (lane >> 4) * 8);
        #pragma unroll
        for (int mt = 0; mt < 4; mt++)
            #pragma unroll
            for (int nt = 0; nt < 4; nt++)
                acc[mt][nt] = __builtin_amdgcn_mfma_f32_16x16x32_bf16(a[mt], b[nt], acc[mt][nt], 0, 0, 0);
    }

    const int row0 = m_base + wr * 64 + (lane >> 4) * 4;
    const int col0 = n_base + wc * 64 + (lane & 15);
    if constexpr (OUT_F32) {
        float* C = (float*)Call + (size_t)blockIdx.z * M * N;
        #pragma unroll
        for (int mt = 0; mt < 4; mt++)
            #pragma unroll
            for (int nt = 0; nt < 4; nt++)
                #pragma unroll
                for (int r = 0; r < 4; r++)
                    C[(size_t)(row0 + mt * 16 + r) * N + col0 + nt * 16] = acc[mt][nt][r];
    } else {
        ushort* C = (ushort*)Call + (size_t)blockIdx.z * M * N;
        #pragma unroll
        for (int mt = 0; mt < 4; mt++)
            #pragma unroll
            for (int nt = 0; nt < 4; nt++)
                #pragma unroll
                for (int r = 0; r < 4; r++)
                    C[(size_t)(row0 + mt * 16 + r) * N + col0 + nt * 16] = f2bf(acc[mt][nt][r]);
    }
}

// ---------------- causal flash attention: persistent 4-wave blocks + work queue ----------------
// 512 persistent blocks (2/CU -> 8 waves/CU = 2 waves/SIMD for latency hiding). Units =
// (qa 0..15, bh 0..31): a 128-row q-block of one head; heavy-first order (qa=15 first);
// blocks pull units via global atomicAdd -> LPT dynamic balance under ANY dispatch order.
// Per unit: 4 waves each own 32 q-rows; ntile = 2qa+2 KV-64 tiles, K/V double-buffered in
// LDS (pad-72, measured conflict-free), 1 barrier/tile, reg-prefetch of tile tt+2.
// Per-wave 32x32 core (verified R8): swapped QK^T, in-register softmax (in-lane tree +
// shfl_xor(32)), zero-shuffle PV with pi baked into V LDS columns, exp2 domain, defer-max,
// setprio. Waves 0,1 skip compute of the final tile (fully past-diagonal).
__global__ __launch_bounds__(256, 2) void attn_kernel(
        const ushort* __restrict__ Qp, const ushort* __restrict__ Kp,
        const ushort* __restrict__ Vp, ushort* __restrict__ Op,
        uint32_t* __restrict__ ctr) {
    __shared__ __attribute__((aligned(16))) ushort Ksh[2][64 * 72];  // [kv][dk]
    __shared__ __attribute__((aligned(16))) ushort Vts[2][64 * 72];  // [dv][kv-permuted]
    __shared__ int unit_j;

    const int tid = threadIdx.x, lane = tid & 63, w = tid >> 6;
    const int m31 = lane & 31, hi = lane >> 5;

    // staging decomposition (256 threads)
    const int kr  = tid >> 3, kck = (tid & 7) * 8;   // K: rows kr, kr+32; 16B col chunk
    const int kvp = tid & 31, dvc = tid >> 5;        // V: kv pair, dv 8-chunk (0..7)
    // pi column permutation: within each 16-kv block swap quads 1<->2 (pair-index space)
    const int lp = kvp & 7, q2 = lp >> 1;
    const int q2p = ((q2 & 1) << 1) | (q2 >> 1);     // 0,1,2,3 -> 0,2,1,3
    const int kvc = (kvp & ~7) | (q2p << 1) | (lp & 1);

    const ushort *Qb, *Kb, *Vb;
    ushort *Ob;
    short8_t kreg0, kreg1, vreg0, vreg1;
    auto LOADKV = [&](int kv0) {
        kreg0 = *(const short8_t*)(Kb + (size_t)(kv0 + kr) * DMODEL + kck);
        kreg1 = *(const short8_t*)(Kb + (size_t)(kv0 + kr + 32) * DMODEL + kck);
        const ushort* vsrc = Vb + (size_t)(kv0 + kvp * 2) * DMODEL + dvc * 8;
        vreg0 = *(const short8_t*)(vsrc);
        vreg1 = *(const short8_t*)(vsrc + DMODEL);
    };
    auto WRITEKV = [&](int buf) {
        *(short8_t*)(&Ksh[buf][kr * 72 + kck]) = kreg0;
        *(short8_t*)(&Ksh[buf][(kr + 32) * 72 + kck]) = kreg1;
        uint4_t a = __builtin_bit_cast(uint4_t, vreg0);      // kv even row
        uint4_t o = __builtin_bit_cast(uint4_t, vreg1);      // kv odd row
        #pragma unroll
        for (int j = 0; j < 4; j++) {
            *(uint32_t*)(&Vts[buf][(dvc * 8 + 2 * j) * 72 + kvc * 2]) =
                __builtin_amdgcn_perm(o[j], a[j], 0x05040100u);
            *(uint32_t*)(&Vts[buf][(dvc * 8 + 2 * j + 1) * 72 + kvc * 2]) =
                __builtin_amdgcn_perm(o[j], a[j], 0x07060302u);
        }
    };

    for (;;) {
        __syncthreads();                   // previous unit fully consumed (LDS + unit_j safe)
        if (tid == 0) unit_j = (int)atomicAdd(ctr, 1u);
        __syncthreads();
        const int j = unit_j;
        if (j >= 512) break;

        const int qa = 15 - (j >> 5);      // heavy units first (LPT)
        const int bh = j & 31;
        const int b = bh >> 4, h = bh & 15;
        Qb = Qp + (size_t)(b * T_SEQ) * DMODEL + h * DHEAD;
        Kb = Kp + (size_t)(b * T_SEQ) * DMODEL + h * DHEAD;
        Vb = Vp + (size_t)(b * T_SEQ) * DMODEL + h * DHEAD;
        Ob = Op + (size_t)(b * T_SEQ) * DMODEL + h * DHEAD;

        const int ntile = 2 * qa + 2;      // kv tiles covering rows [128qa, 128qa+127]
        const int q0w = qa * 128 + w * 32; // this wave's 32 q-rows
        const int qg = q0w + m31;
        const int diag = 2 * qa + (w >> 1);// this wave's diagonal tile

        short8_t qf[4];
        #pragma unroll
        for (int dkc = 0; dkc < 4; dkc++)
            qf[dkc] = *(const short8_t*)(Qb + (size_t)(q0w + m31) * DMODEL + dkc * 16 + hi * 8);

        f32x16 acc0 = {}, acc1 = {};       // O[32q][64dv]
        float mrun = -1e30f, lrun = 0.f;

        LOADKV(0);
        WRITEKV(0);                        // tile 0 -> buf0 (prev unit done: barrier above)
        LOADKV(64);                        // tile 1 -> regs (ntile >= 2 always)

        for (int tt = 0; tt < ntile; ++tt) {
            const int cur = tt & 1;
            __syncthreads();               // buf cur writes visible; cur^1 reads complete
            if (tt + 1 < ntile) {
                WRITEKV(cur ^ 1);
                if (tt + 2 < ntile) LOADKV((tt + 2) * 64);
            }

            if (tt <= diag) {              // waves 0,1 skip the final (past-diagonal) tile
                const int kv0 = tt * 64;
                // S^T = K * Q^T: lane holds S^T[kv][q=m31]; reg r -> kv_local =
                // (r&3)+8*(r>>2)+4*hi  [C/D layout m74/m101]
                f32x16 s0 = {}, s1 = {};
                __builtin_amdgcn_s_setprio(1);
                #pragma unroll
                for (int dkc = 0; dkc < 4; dkc++) {
                    short8_t kf0 = *(const short8_t*)(&Ksh[cur][(m31) * 72 + dkc * 16 + hi * 8]);
                    short8_t kf1 = *(const short8_t*)(&Ksh[cur][(32 + m31) * 72 + dkc * 16 + hi * 8]);
                    s0 = __builtin_amdgcn_mfma_f32_32x32x16_bf16(kf0, qf[dkc], s0, 0, 0, 0);
                    s1 = __builtin_amdgcn_mfma_f32_32x32x16_bf16(kf1, qf[dkc], s1, 0, 0, 0);
                }
                __builtin_amdgcn_s_setprio(0);

                if (tt == diag) {          // causal mask on the diagonal tile only
                    const int kvb = kv0 + 4 * hi;
                    #pragma unroll
                    for (int r = 0; r < 16; r++) {
                        int kvl = (r & 3) + 8 * (r >> 2);
                        if (kvb + kvl      > qg) s0[r] = -1e30f;
                        if (kvb + kvl + 32 > qg) s1[r] = -1e30f;
                    }
                }

                float tm[16];
                #pragma unroll
                for (int r = 0; r < 16; r++) tm[r] = fmaxf(s0[r], s1[r]);
                #pragma unroll
                for (int st = 8; st >= 1; st >>= 1)
                    #pragma unroll
                    for (int i = 0; i < st; i++) tm[i] = fmaxf(tm[i], tm[i + st]);
                float pmax = fmaxf(tm[0], __shfl_xor(tm[0], 32));

                if (!__all(pmax <= mrun + 8.f)) {  // T13 defer-max
                    float mnew = fmaxf(mrun, pmax);
                    float fac = exp2f(mrun - mnew);
                    mrun = mnew;
                    lrun *= fac;
                    #pragma unroll
                    for (int r = 0; r < 16; r++) {
                        float fr = __shfl(fac, (r & 3) + 8 * (r >> 2) + 4 * hi);
                        acc0[r] *= fr; acc1[r] *= fr;
                    }
                }
                float ps[16];
                #pragma unroll
                for (int r = 0; r < 16; r++) {
                    s0[r] = exp2f(s0[r] - mrun);
                    s1[r] = exp2f(s1[r] - mrun);
                    ps[r] = s0[r] + s1[r];
                }
                #pragma unroll
                for (int st = 8; st >= 1; st >>= 1)
                    #pragma unroll
                    for (int i = 0; i < st; i++) ps[i] += ps[i + st];
                lrun += ps[0] + __shfl_xor(ps[0], 32);

                // P -> A-frags (zero-shuffle; V columns pre-permuted), O += P * V
                short8_t pa[4];
                pa[0] = pack8<0>(s0);
                pa[1] = pack8<8>(s0);
                pa[2] = pack8<0>(s1);
                pa[3] = pack8<8>(s1);
                __builtin_amdgcn_s_setprio(1);
                #pragma unroll
                for (int ks = 0; ks < 4; ks++) {
                    short8_t vf0 = *(const short8_t*)(&Vts[cur][(m31) * 72 + ks * 16 + hi * 8]);
                    short8_t vf1 = *(const short8_t*)(&Vts[cur][(32 + m31) * 72 + ks * 16 + hi * 8]);
                    acc0 = __builtin_amdgcn_mfma_f32_32x32x16_bf16(pa[ks], vf0, acc0, 0, 0, 0);
                    acc1 = __builtin_amdgcn_mfma_f32_32x32x16_bf16(pa[ks], vf1, acc1, 0, 0, 0);
                }
                __builtin_amdgcn_s_setprio(0);
            }
        }

        // normalize + store: O row q=(r&3)+8(r>>2)+4hi, col dv=m31 / 32+m31
        float linv = __builtin_amdgcn_rcpf(lrun);
        #pragma unroll
        for (int r = 0; r < 16; r++) {
            int ql = (r & 3) + 8 * (r >> 2) + 4 * hi;
            float li = __shfl(linv, ql);
            ushort* orow = Ob + (size_t)(q0w + ql) * DMODEL + m31;
            orow[0]  = f2bf(acc0[r] * li);
            orow[32] = f2bf(acc1[r] * li);
        }
    }
}

// ---------------- launch ----------------
extern "C" void kernel_launch(void* const* d_in, const int* in_sizes, int n_in,
                              void* d_out, int out_size, void* d_ws, size_t ws_size,
                              hipStream_t stream) {
    (void)in_sizes; (void)n_in; (void)out_size; (void)ws_size;
    const float* q  = (const float*)d_in[0];
    const float* k  = (const float*)d_in[1];
    const float* v  = (const float*)d_in[2];
    // d_in[3] = mask (causal tril) -- implemented analytically
    const float* Wq = (const float*)d_in[4];
    const float* Wk = (const float*)d_in[5];
    const float* Wv = (const float*)d_in[6];
    const float* Wo = (const float*)d_in[7];

    ushort* ws = (ushort*)d_ws;
    const size_t MK = (size_t)MTOT * DMODEL;    // 4194304 elems
    const size_t NK = (size_t)DMODEL * DMODEL;  // 1048576 elems
    ushort* qkvb = ws;                    // bf16 q,k,v        [3*MK]   (24 MB)
    ushort* wt   = ws + 3 * MK;           // bf16 W^T x4       [4*NK]   ( 8 MB)
    ushort* qkvp = ws + 3 * MK + 4 * NK;  // bf16 Q,K,V proj   [3*MK]   (24 MB)
    ushort* Op   = ws;                    // attn out reuses qkvb region ( 8 MB)
    uint32_t* ctr = (uint32_t*)(ws + 3 * MK + 4 * NK + 3 * MK);  // work-queue counter

    convert_qkv_kernel<<<dim3(12288), dim3(256), 0, stream>>>(q, k, v, qkvb);
    convw_kernel<<<dim3(32, 32, 4), dim3(32, 8), 0, stream>>>(Wq, Wk, Wv, Wo, wt);
    zero_ctr_kernel<<<dim3(1), dim3(64), 0, stream>>>(ctr);
    gemm_bt_kernel<false><<<dim3(32, 8, 3), dim3(256), 0, stream>>>(qkvb, wt, (void*)qkvp,
                                                                    MTOT, DMODEL, DMODEL);
    attn_kernel<<<dim3(512), dim3(256), 0, stream>>>(qkvp, qkvp + MK, qkvp + 2 * MK, Op, ctr);
    gemm_bt_kernel<true><<<dim3(32, 8, 1), dim3(256), 0, stream>>>(Op, wt + 3 * NK, d_out,
                                                                   MTOT, DMODEL, DMODEL);
}